// Round 4
// baseline (336.679 us; speedup 1.0000x reference)
//
#include <hip/hip_runtime.h>
#include <math.h>

#define SUM_H 224
#define SUM_W 221
#define ROWP  224   // padded row stride (floats); level offsets {0,128,192} are 16B-aligned

typedef float f32x4 __attribute__((ext_vector_type(4)));
typedef float f32x2 __attribute__((ext_vector_type(2)));

__device__ __forceinline__ f32x4 ldnt4(const float* p) {
    return __builtin_nontemporal_load((const f32x4*)p);
}
__device__ __forceinline__ f32x2 ldnt2(const float* p) {
    return __builtin_nontemporal_load((const f32x2*)p);
}

// ---------------------------------------------------------------------------
// Kernel 1: per selected gene, softmax widths -> bin-edge table only.
//   bl_t : bin edges (leading 0, trailing forced 1.0), level offs {0,128,192},
//          counts {128,64,32}. Widths derived later as bl[k+1]-bl[k].
// ---------------------------------------------------------------------------
__global__ __launch_bounds__(64) void gene_tables_kernel(
    const float* __restrict__ widths_weight,
    const int*   __restrict__ genes_oi,
    float* __restrict__ bl_t,
    int n_genes)
{
    int g = blockIdx.x;
    if (g >= n_genes) return;
    int gi = genes_oi[g];
    int l  = threadIdx.x;

    const float* wsrc  = widths_weight + (size_t)gi * SUM_W;
    float*       bldst = bl_t + (size_t)g * ROWP;

    const int ns[3]   = {128, 64, 32};
    const int woff[3] = {0, 127, 190};
    const int toff[3] = {0, 128, 192};

    for (int lev = 0; lev < 3; lev++) {
        int m  = ns[lev] - 1;
        int j0 = 2 * l, j1 = 2 * l + 1;
        float u0 = (j0 < m) ? wsrc[woff[lev] + j0] : -1e30f;
        float u1 = (j1 < m) ? wsrc[woff[lev] + j1] : -1e30f;
        float mx = fmaxf(u0, u1);
        #pragma unroll
        for (int msk = 32; msk >= 1; msk >>= 1)
            mx = fmaxf(mx, __shfl_xor(mx, msk, 64));
        float e0 = (j0 < m) ? __expf(u0 - mx) : 0.f;
        float e1 = (j1 < m) ? __expf(u1 - mx) : 0.f;
        float local = e0 + e1;
        float incl  = local;
        #pragma unroll
        for (int off = 1; off < 64; off <<= 1) {
            float t = __shfl_up(incl, off, 64);
            if (l >= off) incl += t;
        }
        float total = __shfl(incl, 63, 64);
        float inv   = 1.0f / total;
        float excl  = incl - local;
        float c0 = (excl + e0) * inv;
        float c1 = (excl + e0 + e1) * inv;
        if (j0 <= m - 2) bldst[toff[lev] + j0 + 1] = c0;
        if (j1 <= m - 2) bldst[toff[lev] + j1 + 1] = c1;
        if (l == 0) {
            bldst[toff[lev]]     = 0.0f;
            bldst[toff[lev] + m] = 1.0f;
        }
    }
}

// ---------------------------------------------------------------------------
// DPP 16-lane rotate-reductions (a DPP "row" == the 16-lane point group).
// ---------------------------------------------------------------------------
template<int CTRL>
__device__ __forceinline__ float dppf(float v) {
    return __builtin_bit_cast(float,
        __builtin_amdgcn_update_dpp(0, __builtin_bit_cast(int, v), CTRL, 0xF, 0xF, true));
}
template<int CTRL>
__device__ __forceinline__ int dppi(int v) {
    return __builtin_amdgcn_update_dpp(0, v, CTRL, 0xF, 0xF, true);
}
__device__ __forceinline__ float row16_sum(float v) {
    v += dppf<0x121>(v); v += dppf<0x122>(v); v += dppf<0x124>(v); v += dppf<0x128>(v);
    return v;
}
__device__ __forceinline__ int row16_sum_i(int v) {
    v += dppi<0x121>(v); v += dppi<0x122>(v); v += dppi<0x124>(v); v += dppi<0x128>(v);
    return v;
}

// ---------------------------------------------------------------------------
// Per-level machinery: 16 lanes per point; lane e owns elems [K*e, K*e+K).
// ---------------------------------------------------------------------------
template<int K>
struct Lvl {
    float E[K + 1];   // staged uh, then E = exp(uh+dh); E[K] = neighbor's E[0]
    float bl[K];
    float wh[K];      // 0.5*width from bl diffs
    float s[K];       // staged dh, then trapezoid masses
    float bln;        // neighbor lane's bl[0]
    float inva;       // 1/area
    float larea;      // log(area)
};

template<int K>
__device__ __forceinline__ void lvl_fetch(const float* __restrict__ dh,
                                          const float* __restrict__ uh,
                                          const float* __restrict__ blp,
                                          int e, Lvl<K>& L)
{
    const int j = K * e;
    if constexpr (K == 8) {
        f32x4 d0 = ldnt4(dh + j), d1 = ldnt4(dh + j + 4);
        *(float4*)&L.E[0]  = *(const float4*)(uh  + j);
        *(float4*)&L.E[4]  = *(const float4*)(uh  + j + 4);
        *(float4*)&L.bl[0] = *(const float4*)(blp + j);
        *(float4*)&L.bl[4] = *(const float4*)(blp + j + 4);
        #pragma unroll
        for (int k = 0; k < 4; k++) { L.s[k] = d0[k]; L.s[4 + k] = d1[k]; }
    } else if constexpr (K == 4) {
        f32x4 d0 = ldnt4(dh + j);
        *(float4*)&L.E[0]  = *(const float4*)(uh  + j);
        *(float4*)&L.bl[0] = *(const float4*)(blp + j);
        #pragma unroll
        for (int k = 0; k < 4; k++) L.s[k] = d0[k];
    } else {
        f32x2 d0 = ldnt2(dh + j);
        *(float2*)&L.E[0]  = *(const float2*)(uh  + j);
        *(float2*)&L.bl[0] = *(const float2*)(blp + j);
        L.s[0] = d0[0]; L.s[1] = d0[1];
    }
}

template<int K>
__device__ __forceinline__ void lvl_finish(int e, Lvl<K>& L)
{
    L.bln = __shfl_down(L.bl[0], 1, 16);          // junk at e==15, masked below
    #pragma unroll
    for (int k = 0; k < K; k++) L.E[k] = __expf(L.E[k] + L.s[k]);
    L.E[K] = __shfl_down(L.E[0], 1, 16);          // junk at e==15, masked below
    #pragma unroll
    for (int k = 0; k < K - 1; k++) L.wh[k] = 0.5f * (L.bl[k + 1] - L.bl[k]);
    L.wh[K - 1] = 0.5f * (L.bln - L.bl[K - 1]);
    #pragma unroll
    for (int k = 0; k < K; k++) L.s[k] = (L.E[k] + L.E[k + 1]) * L.wh[k];
    if (e == 15) L.s[K - 1] = 0.f;                // mass N-1 does not exist
    float a = 0.f;
    #pragma unroll
    for (int k = 0; k < K; k++) a += L.s[k];
    a = row16_sum(a);
    L.inva  = __builtin_amdgcn_rcpf(a);
    L.larea = __logf(a);
}

template<int N, int K>
__device__ __forceinline__ void lvl_apply(const Lvl<K>& L, float& x, float& lad)
{
    constexpr int LOGK = (K == 8) ? 3 : (K == 4) ? 2 : 1;
    bool c[K];
    #pragma unroll
    for (int k = 0; k < K; k++) c[k] = (x >= L.bl[k]);
    bool cn = (x >= L.bln);                        // e15: s[K-1]==0, junk pred harmless

    int   cnt  = 0;
    float part = 0.f;
    #pragma unroll
    for (int k = 0; k < K; k++) cnt += c[k] ? 1 : 0;
    #pragma unroll
    for (int k = 0; k < K - 1; k++) part += c[k + 1] ? L.s[k] : 0.f;
    part += cn ? L.s[K - 1] : 0.f;

    cnt  = row16_sum_i(cnt);
    part = row16_sum(part);

    int idx = cnt - 1;                 // cnt >= 1 since bl[0]=0 <= x
    if (idx > N - 2) idx = N - 2;      // x==1.0; out-clip absorbs part's off-by-one
    const int owner = idx >> LOGK;
    const int slot  = idx & (K - 1);

    float sE = L.E[0], sE1 = L.E[1], sB = L.bl[0], sW = L.wh[0];
    #pragma unroll
    for (int jj = 1; jj < K; jj++) {
        bool m = (slot == jj);
        sE  = m ? L.E[jj]     : sE;
        sE1 = m ? L.E[jj + 1] : sE1;
        sB  = m ? L.bl[jj]    : sB;
        sW  = m ? L.wh[jj]    : sW;
    }
    float El  = __shfl(sE,  owner, 16);
    float Er  = __shfl(sE1, owner, 16);
    float inb = __shfl(sB,  owner, 16);
    float whs = __shfl(sW,  owner, 16);

    float dE    = Er - El;
    float alpha = (x - inb) * __builtin_amdgcn_rcpf(whs + whs);
    float poly  = fmaf(fmaf(whs * dE, alpha, (El + El) * whs), alpha, part);
    float outv  = poly * L.inva;
    lad += __logf(fmaf(alpha, dE, El)) - L.larea;
    x = __builtin_amdgcn_fmed3f(outv, 0.0f, 1.0f);
}

// ---------------------------------------------------------------------------
// Pass 0: level 0 (N=128, K=8).  Pass 12: levels 1+2 (N=64/32).
// ---------------------------------------------------------------------------
__global__ __launch_bounds__(256) void spline_pass0(
    const float* __restrict__ x_in,
    const float* __restrict__ delta,
    const int*   __restrict__ lgx,
    const int*   __restrict__ genes_oi,
    const float* __restrict__ heights_weight,
    const float* __restrict__ bl_t,
    float* __restrict__ x_mid,
    float* __restrict__ lad_mid,
    int n_points)
{
    int tid = blockIdx.x * blockDim.x + threadIdx.x;
    int p = tid >> 4;
    int e = tid & 15;
    if (p >= n_points) return;

    int g  = lgx[p];
    int gi = genes_oi[g];
    const float* dh = delta          + (size_t)p  * SUM_H;
    const float* uh = heights_weight + (size_t)gi * SUM_H;
    const float* bl = bl_t + (size_t)g * ROWP;

    Lvl<8> L0;
    lvl_fetch<8>(dh, uh, bl, e, L0);
    float x = x_in[p];
    float lad = 0.f;
    lvl_finish<8>(e, L0);
    lvl_apply<128, 8>(L0, x, lad);

    if (e == 0) { x_mid[p] = x; lad_mid[p] = lad; }
}

__global__ __launch_bounds__(256) void spline_pass12(
    const float* __restrict__ x_mid,
    const float* __restrict__ lad_mid,
    const float* __restrict__ delta,
    const int*   __restrict__ lgx,
    const int*   __restrict__ genes_oi,
    const float* __restrict__ heights_weight,
    const float* __restrict__ bl_t,
    float* __restrict__ out,
    float* __restrict__ lad_out,
    int n_points)
{
    int tid = blockIdx.x * blockDim.x + threadIdx.x;
    int p = tid >> 4;
    int e = tid & 15;
    if (p >= n_points) return;

    int g  = lgx[p];
    int gi = genes_oi[g];
    const float* dh = delta          + (size_t)p  * SUM_H;
    const float* uh = heights_weight + (size_t)gi * SUM_H;
    const float* bl = bl_t + (size_t)g * ROWP;

    Lvl<4> L1; Lvl<2> L2;
    lvl_fetch<4>(dh + 128, uh + 128, bl + 128, e, L1);
    lvl_fetch<2>(dh + 192, uh + 192, bl + 192, e, L2);
    float x   = x_mid[p];
    float lad = lad_mid[p];
    lvl_finish<4>(e, L1);
    lvl_finish<2>(e, L2);
    lvl_apply<64, 4>(L1, x, lad);
    lvl_apply<32, 2>(L2, x, lad);

    if (e == 0) { out[p] = x; lad_out[p] = lad; }
}

extern "C" void kernel_launch(void* const* d_in, const int* in_sizes, int n_in,
                              void* d_out, int out_size, void* d_ws, size_t ws_size,
                              hipStream_t stream)
{
    const float* x        = (const float*)d_in[0];
    const float* delta    = (const float*)d_in[1];
    const float* hw       = (const float*)d_in[2];
    const float* ww       = (const float*)d_in[3];
    const int*   genes_oi = (const int*)  d_in[4];
    const int*   lgx      = (const int*)  d_in[5];

    int n_points   = in_sizes[0];
    int n_genes_oi = in_sizes[4];

    float* bl_t = (float*)d_ws;
    size_t off  = (((size_t)n_genes_oi * ROWP) + 63) & ~(size_t)63;  // 256B-align
    float* x_mid   = bl_t + off;
    size_t npad    = ((size_t)n_points + 63) & ~(size_t)63;
    float* lad_mid = x_mid + npad;

    hipLaunchKernelGGL(gene_tables_kernel, dim3(n_genes_oi), dim3(64), 0, stream,
                       ww, genes_oi, bl_t, n_genes_oi);

    const int threads = 256;
    const int ppb     = threads / 16;
    const int blocks  = (n_points + ppb - 1) / ppb;
    hipLaunchKernelGGL(spline_pass0, dim3(blocks), dim3(threads), 0, stream,
                       x, delta, lgx, genes_oi, hw, bl_t, x_mid, lad_mid, n_points);
    hipLaunchKernelGGL(spline_pass12, dim3(blocks), dim3(threads), 0, stream,
                       x_mid, lad_mid, delta, lgx, genes_oi, hw, bl_t,
                       (float*)d_out, (float*)d_out + n_points, n_points);
}